// Round 6
// baseline (820.190 us; speedup 1.0000x reference)
//
#include <hip/hip_runtime.h>
#include <hip/hip_bf16.h>
#include <stdint.h>

// Problem dims (fixed by the reference setup)
#define BDIM 8192      // rows of x
#define CDIM 10000     // class means
#define CPAD 10240     // 40 * 256
#define FDIM 2048      // feature dim (K)

#define BM 256
#define BN 256
#define BK 64
#define NT (FDIM / BK)          // 32 K-tiles
#define NI (NT / 2)             // 16 iterations (2 K-tiles each)
#define TM (BDIM / BM)          // 32
#define TN (CPAD / BN)          // 40
#define NWG (TM * TN)           // 1280, multiple of 8

#define HT_BYTES   16384        // one half-tile region (128 rows x 128 B)
#define DBUF_BYTES 65536        // A0|A1|B0|B1
#define EPI_WAVE_BYTES 17408    // 64 rows x 68 f32 (epilogue transpose tile)
#define LDS_BYTES  139264       // max(131072 main loop, 8*17408 epilogue)

typedef __attribute__((ext_vector_type(8)))  __bf16 bf16x8;
typedef __attribute__((ext_vector_type(4)))  float  f32x4;
typedef __attribute__((ext_vector_type(16))) float  f32x16;

#define AS1 __attribute__((address_space(1)))
#define AS3 __attribute__((address_space(3)))

// ---------------------------------------------------------------------------
// Prep (fused): f32 rows -> bf16 rows (RNE) + per-row sum of squares (f32).
// Blocks [0, BDIM) handle x; blocks [BDIM, BDIM+CPAD) handle means (padded).
// ---------------------------------------------------------------------------
__global__ __launch_bounds__(256) void convert_rows(
    const float* __restrict__ xsrc, const float* __restrict__ msrc,
    unsigned short* __restrict__ Xb, unsigned short* __restrict__ Mb,
    float* __restrict__ xsq, float* __restrict__ msq)
{
    const int b = blockIdx.x;
    const int tid = threadIdx.x;

    const float* src;
    unsigned short* drow;
    float* sq;
    int row;
    if (b < BDIM) {
        row = b; src = xsrc + (size_t)row * FDIM;
        drow = Xb + (size_t)row * FDIM; sq = xsq + row;
    } else {
        row = b - BDIM;
        drow = Mb + (size_t)row * FDIM; sq = msq + row;
        if (row >= CDIM) {
            ((uint4*)drow)[tid] = make_uint4(0, 0, 0, 0);
            if (tid == 0) *sq = 0.0f;
            return;
        }
        src = msrc + (size_t)row * FDIM;
    }

    const float4* s = (const float4*)src;
    float4 v0 = s[tid * 2 + 0];
    float4 v1 = s[tid * 2 + 1];

    float f[8] = {v0.x, v0.y, v0.z, v0.w, v1.x, v1.y, v1.z, v1.w};
    float ssum = 0.0f;
    union { unsigned short u[8]; uint4 v; } pk;
#pragma unroll
    for (int j = 0; j < 8; ++j) {
        ssum += f[j] * f[j];
        uint32_t bb = __builtin_bit_cast(uint32_t, f[j]);
        bb = bb + 0x7fffu + ((bb >> 16) & 1u);   // RNE to bf16
        pk.u[j] = (unsigned short)(bb >> 16);
    }
    ((uint4*)drow)[tid] = pk.v;

#pragma unroll
    for (int off = 32; off > 0; off >>= 1)
        ssum += __shfl_down(ssum, off, 64);
    __shared__ float red[4];
    if ((tid & 63) == 0) red[tid >> 6] = ssum;
    __syncthreads();
    if (tid == 0) *sq = red[0] + red[1] + red[2] + red[3];
}

// ---------------------------------------------------------------------------
// 256x256 bf16 GEMM, 8-phase counted-vmcnt schedule with one-phase ds_read
// read-ahead (double-buffered fragment regs) and 32x32x16 MFMA.
// out[i][j] = 2*sum_k X[i][k]*M[j][k] - xsq[i] - msq[j]
// ---------------------------------------------------------------------------
#define MIDSYNC() do { \
    __builtin_amdgcn_s_barrier(); \
    asm volatile("s_waitcnt lgkmcnt(0)" ::: "memory"); \
    __builtin_amdgcn_sched_barrier(0); \
} while (0)

#define ENDBAR() do { \
    __builtin_amdgcn_s_barrier(); \
    __builtin_amdgcn_sched_barrier(0); \
} while (0)

#define SCHEDBAR() __builtin_amdgcn_sched_barrier(0)

// one quadrant: 2 independent 32x32 acc chains x 4 K-steps
#define QUAD32(MH, NH, AV, BV) do { \
    __builtin_amdgcn_s_setprio(1); \
    _Pragma("unroll") \
    for (int ks = 0; ks < 4; ++ks) \
      _Pragma("unroll") \
      for (int f2 = 0; f2 < 2; ++f2) \
        acc[(MH)*2+f2][NH] = __builtin_amdgcn_mfma_f32_32x32x16_bf16( \
            AV[f2][ks], BV[ks], acc[(MH)*2+f2][NH], 0, 0, 0); \
    __builtin_amdgcn_s_setprio(0); \
} while (0)

__global__ __launch_bounds__(512, 2) void nscm_gemm(
    const unsigned short* __restrict__ Xb, const unsigned short* __restrict__ Mb,
    const float* __restrict__ xsq, const float* __restrict__ msq,
    float* __restrict__ out)
{
    extern __shared__ char lds[];

    const int tid  = threadIdx.x;
    const int lane = tid & 63;
    const int wave = tid >> 6;       // 0..7
    const int wr = wave >> 2;        // 0..1  (M half)
    const int wc = wave & 3;         // 0..3  (N quarter)
    const int l31 = lane & 31;
    const int l7  = lane & 7;
    const int khi = (lane >> 5) * 16;   // byte offset of k-subgroup

    // T1 + 2D clustering: xcd slab = 4 rows x 40 cols, five 4x8 sub-rects
    const int bid = blockIdx.x;
    const int xcd = bid & 7;
    const int c   = bid >> 3;            // 0..159 within XCD slab
    const int sub = c >> 5;              // 0..4   (column group of 8)
    const int tile_m = xcd * 4 + (c & 3);
    const int tile_n = sub * 8 + ((c >> 2) & 7);
    const int row0 = tile_m * BM;
    const int col0 = tile_n * BN;

    const int w8  = tid >> 3;                          // wave*8 + lane>>3
    const int sce = ((tid & 7) ^ (w8 & 7)) * 8;        // pre-swizzled src col (elems)

    f32x16 acc[4][2] = {};
    bf16x8 av0[2][4], av1[2][4], bv0[4], bv1[4];

    // stage one A half-tile (h: rows with bit6==h) of K-tile kt into buf
    auto stageA = [&](int kt, int buf, int h) {
#pragma unroll
        for (int l = 0; l < 2; ++l) {
            const int w = l * 64 + w8;                           // 0..127 in-half
            const int grow = row0 + (w >> 6) * 128 + h * 64 + (w & 63);
            const unsigned short* src = Xb + (size_t)grow * FDIM + kt * BK + sce;
            char* dst = lds + buf * DBUF_BYTES + h * HT_BYTES
                        + (l * 64 + wave * 8) * 128;
            __builtin_amdgcn_global_load_lds((const AS1 void*)src,
                                             (AS3 void*)dst, 16, 0, 0);
        }
    };
    // stage one B half-tile (h: rows with bit5==h)
    auto stageB = [&](int kt, int buf, int h) {
#pragma unroll
        for (int l = 0; l < 2; ++l) {
            const int w = l * 64 + w8;
            const int grow = col0 + (w >> 5) * 64 + h * 32 + (w & 31);
            const unsigned short* src = Mb + (size_t)grow * FDIM + kt * BK + sce;
            char* dst = lds + buf * DBUF_BYTES + 32768 + h * HT_BYTES
                        + (l * 64 + wave * 8) * 128;
            __builtin_amdgcn_global_load_lds((const AS1 void*)src,
                                             (AS3 void*)dst, 16, 0, 0);
        }
    };

    // 32x32x16 A fragment: lane holds row l&31, k-bytes (l>>5)*16 + j
    auto loadA32 = [&](int buf, int mh, bf16x8 (&dst)[2][4]) {
        const char* base = lds + buf * DBUF_BYTES + mh * HT_BYTES;
#pragma unroll
        for (int f2 = 0; f2 < 2; ++f2) {
            const int row = wr * 64 + f2 * 32 + l31;   // within 128-row half
#pragma unroll
            for (int ks = 0; ks < 4; ++ks)
                dst[f2][ks] = *(const bf16x8*)(base + row * 128 +
                                ((ks * 32 + khi) ^ (l7 << 4)));
        }
    };
    auto loadB32 = [&](int buf, int nh, bf16x8 (&dst)[4]) {
        const char* base = lds + buf * DBUF_BYTES + 32768 + nh * HT_BYTES;
        const int row = wc * 32 + l31;                 // within 128-row half
#pragma unroll
        for (int ks = 0; ks < 4; ++ks)
            dst[ks] = *(const bf16x8*)(base + row * 128 +
                            ((ks * 32 + khi) ^ (l7 << 4)));
    };

    // prologue: 7 half-tiles (buf0 tile0 complete + 3/4 of buf1 tile1)
    stageA(0, 0, 0); stageB(0, 0, 0); stageB(0, 0, 1); stageA(0, 0, 1);
    stageA(1, 1, 0); stageB(1, 1, 0); stageB(1, 1, 1);
    asm volatile("s_waitcnt vmcnt(6)" ::: "memory");   // buf0 tile0 landed
    __builtin_amdgcn_s_barrier();
    SCHEDBAR();
    loadA32(0, 0, av0); loadB32(0, 0, bv0);            // R(Q1) for t=0
    SCHEDBAR();

    for (int t = 0; t < NI; ++t) {
        const int kO1 = 2 * t + 1;                 // odd tile (buf1), valid
        const int kE2 = (2 * t + 2) & (NT - 1);    // next even (dummy-wraps at end)
        const int kO3 = (2 * t + 3) & (NT - 1);    // next odd

        // ph1: Q1 = (mh0,nh0) buf0; stage Ah1(buf1, 2t+1); R(Q2)=B0h1
        stageA(kO1, 1, 1);
        MIDSYNC();
        loadB32(0, 1, bv1);
        SCHEDBAR();
        QUAD32(0, 0, av0, bv0);
        ENDBAR();

        // ph2: Q2 = (mh0,nh1) buf0; stage Ah0(buf0, 2t+2); R(Q3)=A0h1
        stageA(kE2, 0, 0);
        MIDSYNC();
        loadA32(0, 1, av1);
        SCHEDBAR();
        QUAD32(0, 1, av0, bv1);
        ENDBAR();

        // ph3: Q3 = (mh1,nh0) buf0; stage Bh0(buf0, 2t+2)
        stageB(kE2, 0, 0);
        MIDSYNC();
        QUAD32(1, 0, av1, bv0);
        ENDBAR();

        // ph4: Q4 = (mh1,nh1) buf0; stage Bh1(buf0, 2t+2); vmcnt;
        //      R(Q5) = A1h0,B1h0 (buf1 tile 2t+1, landed by this vmcnt)
        stageB(kE2, 0, 1);
        asm volatile("s_waitcnt vmcnt(6)" ::: "memory");
        MIDSYNC();
        loadA32(1, 0, av0); loadB32(1, 0, bv0);
        SCHEDBAR();
        QUAD32(1, 1, av1, bv1);
        ENDBAR();

        // ph5: Q5 = (mh0,nh0) buf1; stage Ah1(buf0, 2t+2); R(Q6)=B1h1
        stageA(kE2, 0, 1);
        MIDSYNC();
        loadB32(1, 1, bv1);
        SCHEDBAR();
        QUAD32(0, 0, av0, bv0);
        ENDBAR();

        // ph6: Q6 = (mh0,nh1) buf1; stage Ah0(buf1, 2t+3); R(Q7)=A1h1
        stageA(kO3, 1, 0);
        MIDSYNC();
        loadA32(1, 1, av1);
        SCHEDBAR();
        QUAD32(0, 1, av0, bv1);
        ENDBAR();

        // ph7: Q7 = (mh1,nh0) buf1; stage Bh0(buf1, 2t+3)
        stageB(kO3, 1, 0);
        MIDSYNC();
        QUAD32(1, 0, av1, bv0);
        ENDBAR();

        // ph8: Q8 = (mh1,nh1) buf1; stage Bh1(buf1, 2t+3); vmcnt;
        //      R(Q1 next) = A0h0,B0h0 (buf0 tile 2t+2, landed by this vmcnt)
        stageB(kO3, 1, 1);
        asm volatile("s_waitcnt vmcnt(6)" ::: "memory");
        MIDSYNC();
        loadA32(0, 0, av0); loadB32(0, 0, bv0);
        SCHEDBAR();
        QUAD32(1, 1, av1, bv1);
        ENDBAR();
    }

    // drain dummy stages + dead read-aheads; sync before epilogue reuses LDS
    asm volatile("s_waitcnt vmcnt(0) lgkmcnt(0)" ::: "memory");
    __builtin_amdgcn_s_barrier();
    SCHEDBAR();

    // ---- epilogue: per-wave LDS transpose -> coalesced float4 nt stores ----
    // 32x32 C layout: col = lane&31, row = (reg&3) + 8*(reg>>2) + 4*(lane>>5)
    float* wtile = (float*)(lds + wave * EPI_WAVE_BYTES);  // [64][68] f32
    const int rr = lane >> 4;              // 0..3 (row within 4-row pass)
    const int cq = lane & 15;              // col-quad index
    const int gc = col0 + wc * 64 + cq * 4;
    float ms0 = 0.f, ms1 = 0.f, ms2 = 0.f, ms3 = 0.f;
    if (gc < CDIM) {
        ms0 = msq[gc]; ms1 = msq[gc + 1]; ms2 = msq[gc + 2]; ms3 = msq[gc + 3];
    }
    const int rbase = 4 * (lane >> 5);

#pragma unroll
    for (int mh = 0; mh < 2; ++mh) {
        // scatter acc fragments into the wave's LDS tile (row-major, pad 68)
#pragma unroll
        for (int f2 = 0; f2 < 2; ++f2)
#pragma unroll
            for (int fn = 0; fn < 2; ++fn)
#pragma unroll
                for (int reg = 0; reg < 16; ++reg) {
                    const int lr = f2 * 32 + (reg & 3) + 8 * (reg >> 2) + rbase;
                    const int lc = fn * 32 + l31;
                    wtile[lr * 68 + lc] = acc[mh * 2 + f2][fn][reg];
                }
        asm volatile("s_waitcnt lgkmcnt(0)" ::: "memory");
        SCHEDBAR();

        if (gc < CDIM) {
#pragma unroll
            for (int i = 0; i < 16; ++i) {
                const int row = i * 4 + rr;
                f32x4 v = *(const f32x4*)&wtile[row * 68 + cq * 4];
                const int gr = row0 + wr * 128 + mh * 64 + row;
                const float xsv = xsq[gr];
                f32x4 o;
                o[0] = 2.0f * v[0] - xsv - ms0;
                o[1] = 2.0f * v[1] - xsv - ms1;
                o[2] = 2.0f * v[2] - xsv - ms2;
                o[3] = 2.0f * v[3] - xsv - ms3;
                __builtin_nontemporal_store(
                    o, (f32x4*)(out + (size_t)gr * CDIM + gc));
            }
        }
        // wave-local reuse of wtile in next mh: ensure reads retired
        asm volatile("s_waitcnt lgkmcnt(0)" ::: "memory");
        SCHEDBAR();
    }
}

// ---------------------------------------------------------------------------
extern "C" void kernel_launch(void* const* d_in, const int* in_sizes, int n_in,
                              void* d_out, int out_size, void* d_ws, size_t ws_size,
                              hipStream_t stream) {
    const float* x     = (const float*)d_in[0];   // [8192, 2048]
    const float* means = (const float*)d_in[1];   // [10000, 2048]
    float* out = (float*)d_out;                   // [8192, 10000]

    char* ws = (char*)d_ws;
    unsigned short* Xb = (unsigned short*)ws;                             // 8192*2048 bf16
    unsigned short* Mb = (unsigned short*)(ws + (size_t)BDIM * FDIM * 2); // 10240*2048 bf16
    float* xsq = (float*)(ws + (size_t)BDIM * FDIM * 2 + (size_t)CPAD * FDIM * 2);
    float* msq = xsq + BDIM;

    (void)hipFuncSetAttribute((const void*)nscm_gemm,
                              hipFuncAttributeMaxDynamicSharedMemorySize,
                              LDS_BYTES);

    convert_rows<<<BDIM + CPAD, 256, 0, stream>>>(x, means, Xb, Mb, xsq, msq);

    nscm_gemm<<<NWG, 512, LDS_BYTES, stream>>>(Xb, Mb, xsq, msq, out);
}

// Round 7
// 213.080 us; speedup vs baseline: 3.8492x; 3.8492x over previous
//
#include <hip/hip_runtime.h>
#include <hip/hip_bf16.h>
#include <stdint.h>

// Problem dims (fixed by the reference setup)
#define BDIM 8192      // rows of x
#define CDIM 10000     // class means
#define CPAD 10240     // 40 * 256
#define FDIM 2048      // feature dim (K)

#define BM 256
#define BN 256
#define BKB 128                 // K-chunk = 128 i8 elems = 128 bytes per row
#define NT (FDIM / BKB)         // 16 K-chunks
#define NI (NT / 2)             // 8 iterations (2 K-chunks each)
#define TM (BDIM / BM)          // 32
#define TN (CPAD / BN)          // 40
#define NWG (TM * TN)           // 1280, multiple of 8

#define HT_BYTES   16384        // one half-tile region (128 rows x 128 B)
#define DBUF_BYTES 65536        // A0|A1|B0|B1
#define EPI_WAVE_BYTES 17408    // 64 rows x 68 f32 (epilogue transpose tile)
#define LDS_BYTES  139264       // max(131072 main loop, 8*17408 epilogue)

// int8 quantization: step q = QS, symmetric [-127,127]
#define QSF   (6.5f / 127.0f)
#define INVQ  (127.0f / 6.5f)
#define TSC   (2.0f * QSF * QSF)

typedef __attribute__((ext_vector_type(4))) int   i32x4;
typedef __attribute__((ext_vector_type(4))) float f32x4;

#define AS1 __attribute__((address_space(1)))
#define AS3 __attribute__((address_space(3)))

// ---------------------------------------------------------------------------
// Prep (fused): f32 rows -> i8 rows (RNE quant, clamp +-127) + per-row sum of
// squares in f32 (exact). Blocks [0,BDIM) = x; [BDIM, BDIM+CPAD) = means.
// ---------------------------------------------------------------------------
__global__ __launch_bounds__(256) void convert_rows(
    const float* __restrict__ xsrc, const float* __restrict__ msrc,
    signed char* __restrict__ Xq, signed char* __restrict__ Mq,
    float* __restrict__ xsq, float* __restrict__ msq)
{
    const int b = blockIdx.x;
    const int tid = threadIdx.x;

    const float* src;
    signed char* drow;
    float* sq;
    int row;
    if (b < BDIM) {
        row = b; src = xsrc + (size_t)row * FDIM;
        drow = Xq + (size_t)row * FDIM; sq = xsq + row;
    } else {
        row = b - BDIM;
        drow = Mq + (size_t)row * FDIM; sq = msq + row;
        if (row >= CDIM) {
            ((uint2*)drow)[tid] = make_uint2(0, 0);
            if (tid == 0) *sq = 0.0f;
            return;
        }
        src = msrc + (size_t)row * FDIM;
    }

    const float4* s = (const float4*)src;
    float4 v0 = s[tid * 2 + 0];
    float4 v1 = s[tid * 2 + 1];

    float f[8] = {v0.x, v0.y, v0.z, v0.w, v1.x, v1.y, v1.z, v1.w};
    float ssum = 0.0f;
    union { unsigned char u[8]; uint2 v; } pk;
#pragma unroll
    for (int j = 0; j < 8; ++j) {
        ssum += f[j] * f[j];
        int q = (int)__builtin_rintf(f[j] * INVQ);
        q = q > 127 ? 127 : (q < -127 ? -127 : q);
        pk.u[j] = (unsigned char)(q & 0xff);
    }
    ((uint2*)drow)[tid] = pk.v;

#pragma unroll
    for (int off = 32; off > 0; off >>= 1)
        ssum += __shfl_down(ssum, off, 64);
    __shared__ float red[4];
    if ((tid & 63) == 0) red[tid >> 6] = ssum;
    __syncthreads();
    if (tid == 0) *sq = red[0] + red[1] + red[2] + red[3];
}

// ---------------------------------------------------------------------------
// 256x256 int8 GEMM (mfma_i32_16x16x64_i8), 8-phase counted-vmcnt schedule
// (T1+T2+T3+T4+T5), byte-identical staging/fragment addressing to the proven
// bf16 R5 structure (128-B rows; 16 B per lane fragment).
// out[i][j] = 2*QS^2*acc_int - xsq[i] - msq[j]
// Epilogue: per-wave LDS transpose -> coalesced float4 nontemporal stores.
// ---------------------------------------------------------------------------
#define MIDSYNC() do { \
    __builtin_amdgcn_s_barrier(); \
    asm volatile("s_waitcnt lgkmcnt(0)" ::: "memory"); \
    __builtin_amdgcn_sched_barrier(0); \
} while (0)

#define ENDBAR() do { \
    __builtin_amdgcn_s_barrier(); \
    __builtin_amdgcn_sched_barrier(0); \
} while (0)

// ks outermost: the two MFMAs accumulating into the same acc are 8 apart
#define QUAD(MH, BV, NH) do { \
    __builtin_amdgcn_s_setprio(1); \
    _Pragma("unroll") \
    for (int ks = 0; ks < 2; ++ks) \
      _Pragma("unroll") \
      for (int f = 0; f < 4; ++f) \
        _Pragma("unroll") \
        for (int f2 = 0; f2 < 2; ++f2) \
          acc[(MH)*4+f][(NH)*2+f2] = __builtin_amdgcn_mfma_i32_16x16x64_i8( \
              av[f][ks], BV[f2][ks], acc[(MH)*4+f][(NH)*2+f2], 0, 0, 0); \
    __builtin_amdgcn_s_setprio(0); \
} while (0)

__global__ __launch_bounds__(512, 2) void nscm_gemm(
    const signed char* __restrict__ Xq, const signed char* __restrict__ Mq,
    const float* __restrict__ xsq, const float* __restrict__ msq,
    float* __restrict__ out)
{
    extern __shared__ char lds[];

    const int tid  = threadIdx.x;
    const int lane = tid & 63;
    const int wave = tid >> 6;       // 0..7
    const int wr = wave >> 2;        // 0..1  (M half)
    const int wc = wave & 3;         // 0..3  (N quarter)
    const int fr = lane & 15;
    const int kq = lane >> 4;        // 0..3

    // T1 + 2D clustering: xcd slab = 4 rows x 40 cols, five 4x8 sub-rects
    const int bid = blockIdx.x;
    const int xcd = bid & 7;
    const int c   = bid >> 3;            // 0..159 within XCD slab
    const int sub = c >> 5;              // 0..4   (column group of 8)
    const int tile_m = xcd * 4 + (c & 3);
    const int tile_n = sub * 8 + ((c >> 2) & 7);
    const int row0 = tile_m * BM;
    const int col0 = tile_n * BN;

    const int w8  = tid >> 3;                          // wave*8 + lane>>3
    const int sce = ((tid & 7) ^ (w8 & 7)) * 16;       // pre-swizzled src col (bytes)
    const int xorv = (fr & 7) << 4;                    // T2 read-side XOR

    i32x4 acc[8][4] = {};
    i32x4 av[4][2], bv0[2][2], bv1[2][2];

    // stage one A half-tile (h: rows with bit6==h) of K-chunk kt into buf
    auto stageA = [&](int kt, int buf, int h) {
#pragma unroll
        for (int l = 0; l < 2; ++l) {
            const int w = l * 64 + w8;                           // 0..127 in-half
            const int grow = row0 + (w >> 6) * 128 + h * 64 + (w & 63);
            const signed char* src = Xq + (size_t)grow * FDIM + kt * BKB + sce;
            char* dst = lds + buf * DBUF_BYTES + h * HT_BYTES
                        + (l * 64 + wave * 8) * 128;
            __builtin_amdgcn_global_load_lds((const AS1 void*)src,
                                             (AS3 void*)dst, 16, 0, 0);
        }
    };
    // stage one B half-tile (h: rows with bit5==h)
    auto stageB = [&](int kt, int buf, int h) {
#pragma unroll
        for (int l = 0; l < 2; ++l) {
            const int w = l * 64 + w8;
            const int grow = col0 + (w >> 5) * 64 + h * 32 + (w & 31);
            const signed char* src = Mq + (size_t)grow * FDIM + kt * BKB + sce;
            char* dst = lds + buf * DBUF_BYTES + 32768 + h * HT_BYTES
                        + (l * 64 + wave * 8) * 128;
            __builtin_amdgcn_global_load_lds((const AS1 void*)src,
                                             (AS3 void*)dst, 16, 0, 0);
        }
    };

    auto loadA = [&](int buf, int mh) {
        const char* base = lds + buf * DBUF_BYTES + mh * HT_BYTES;
#pragma unroll
        for (int f = 0; f < 4; ++f) {
            const int w = wr * 64 + f * 16 + fr;
#pragma unroll
            for (int ks = 0; ks < 2; ++ks)
                av[f][ks] = *(const i32x4*)(base + w * 128 +
                                            ((ks * 64 + kq * 16) ^ xorv));
        }
    };
    auto loadB = [&](int buf, int nh, i32x4 (&bv)[2][2]) {
        const char* base = lds + buf * DBUF_BYTES + 32768 + nh * HT_BYTES;
#pragma unroll
        for (int f = 0; f < 2; ++f) {
            const int w = wc * 32 + f * 16 + fr;
#pragma unroll
            for (int ks = 0; ks < 2; ++ks)
                bv[f][ks] = *(const i32x4*)(base + w * 128 +
                                            ((ks * 64 + kq * 16) ^ xorv));
        }
    };

    // prologue: 7 half-tiles (buf0 chunk0 complete + 3/4 of buf1 chunk1)
    stageA(0, 0, 0); stageB(0, 0, 0); stageB(0, 0, 1); stageA(0, 0, 1);
    stageA(1, 1, 0); stageB(1, 1, 0); stageB(1, 1, 1);
    asm volatile("s_waitcnt vmcnt(6)" ::: "memory");   // buf0 chunk0 landed
    __builtin_amdgcn_s_barrier();
    __builtin_amdgcn_sched_barrier(0);

    for (int t = 0; t < NI; ++t) {
        const int kO1 = 2 * t + 1;                 // odd chunk (buf1), valid
        const int kE2 = (2 * t + 2) & (NT - 1);    // next even (dummy-wraps at end)
        const int kO3 = (2 * t + 3) & (NT - 1);    // next odd

        // ph1: reads A(mh0),B(nh0) of buf0; stage Ah1(buf1, chunk 2t+1)
        loadA(0, 0); loadB(0, 0, bv0);
        stageA(kO1, 1, 1);
        asm volatile("s_waitcnt lgkmcnt(8)" ::: "memory");
        MIDSYNC();
        QUAD(0, bv0, 0);
        ENDBAR();

        // ph2: reads B(nh1) of buf0; stage Ah0(buf0, 2t+2)
        loadB(0, 1, bv1);
        stageA(kE2, 0, 0);
        MIDSYNC();
        QUAD(0, bv1, 1);
        ENDBAR();

        // ph3: reads A(mh1) of buf0; stage Bh0(buf0, 2t+2)
        loadA(0, 1);
        stageB(kE2, 0, 0);
        MIDSYNC();
        QUAD(1, bv0, 0);
        ENDBAR();

        // ph4: stage Bh1(buf0, 2t+2); counted vmcnt
        stageB(kE2, 0, 1);
        asm volatile("s_waitcnt vmcnt(6)" ::: "memory");
        MIDSYNC();
        QUAD(1, bv1, 1);
        ENDBAR();

        // ph5: reads A(mh0),B(nh0) of buf1; stage Ah1(buf0, 2t+2)
        loadA(1, 0); loadB(1, 0, bv0);
        stageA(kE2, 0, 1);
        asm volatile("s_waitcnt lgkmcnt(8)" ::: "memory");
        MIDSYNC();
        QUAD(0, bv0, 0);
        ENDBAR();

        // ph6: reads B(nh1) of buf1; stage Ah0(buf1, 2t+3)
        loadB(1, 1, bv1);
        stageA(kO3, 1, 0);
        MIDSYNC();
        QUAD(0, bv1, 1);
        ENDBAR();

        // ph7: reads A(mh1) of buf1; stage Bh0(buf1, 2t+3)
        loadA(1, 1);
        stageB(kO3, 1, 0);
        MIDSYNC();
        QUAD(1, bv0, 0);
        ENDBAR();

        // ph8: stage Bh1(buf1, 2t+3); counted vmcnt
        stageB(kO3, 1, 1);
        asm volatile("s_waitcnt vmcnt(6)" ::: "memory");
        MIDSYNC();
        QUAD(1, bv1, 1);
        ENDBAR();
    }

    // drain dummy stages (they write LDS) and sync before epilogue reuses LDS
    asm volatile("s_waitcnt vmcnt(0)" ::: "memory");
    __builtin_amdgcn_s_barrier();
    __builtin_amdgcn_sched_barrier(0);

    // ---- epilogue: per-wave LDS transpose -> coalesced float4 nt stores ----
    // out[i][j] = TSC*acc - xsq[i] - msq[j]
    float* wtile = (float*)(lds + wave * EPI_WAVE_BYTES);  // [64][68] f32
    const int rr = lane >> 4;              // 0..3 (row within 4-row pass)
    const int cq = lane & 15;              // col-quad index
    const int gc = col0 + wc * 64 + cq * 4;
    float ms0 = 0.f, ms1 = 0.f, ms2 = 0.f, ms3 = 0.f;
    if (gc < CDIM) {
        ms0 = msq[gc]; ms1 = msq[gc + 1]; ms2 = msq[gc + 2]; ms3 = msq[gc + 3];
    }

#pragma unroll
    for (int mh = 0; mh < 2; ++mh) {
        // scatter acc fragments into the wave's LDS tile (row-major, pad 68)
#pragma unroll
        for (int f = 0; f < 4; ++f)
#pragma unroll
            for (int fn = 0; fn < 4; ++fn) {
                const int lr = f * 16 + kq * 4;
                const int lc = fn * 16 + fr;
#pragma unroll
                for (int r = 0; r < 4; ++r)
                    wtile[(lr + r) * 68 + lc] = (float)acc[mh * 4 + f][fn][r];
            }
        asm volatile("s_waitcnt lgkmcnt(0)" ::: "memory");
        __builtin_amdgcn_sched_barrier(0);

        if (gc < CDIM) {
#pragma unroll
            for (int i = 0; i < 16; ++i) {
                const int row = i * 4 + rr;
                f32x4 v = *(const f32x4*)&wtile[row * 68 + cq * 4];
                const int gr = row0 + wr * 128 + mh * 64 + row;
                const float xsv = xsq[gr];
                f32x4 o;
                o[0] = TSC * v[0] - xsv - ms0;
                o[1] = TSC * v[1] - xsv - ms1;
                o[2] = TSC * v[2] - xsv - ms2;
                o[3] = TSC * v[3] - xsv - ms3;
                __builtin_nontemporal_store(
                    o, (f32x4*)(out + (size_t)gr * CDIM + gc));
            }
        }
        // wave-local reuse of wtile in next mh: ensure reads retired
        asm volatile("s_waitcnt lgkmcnt(0)" ::: "memory");
        __builtin_amdgcn_sched_barrier(0);
    }
}

// ---------------------------------------------------------------------------
extern "C" void kernel_launch(void* const* d_in, const int* in_sizes, int n_in,
                              void* d_out, int out_size, void* d_ws, size_t ws_size,
                              hipStream_t stream) {
    const float* x     = (const float*)d_in[0];   // [8192, 2048]
    const float* means = (const float*)d_in[1];   // [10000, 2048]
    float* out = (float*)d_out;                   // [8192, 10000]

    char* ws = (char*)d_ws;
    signed char* Xq = (signed char*)ws;                            // 8192*2048 i8
    signed char* Mq = (signed char*)(ws + (size_t)BDIM * FDIM);    // 10240*2048 i8
    float* xsq = (float*)(ws + (size_t)BDIM * FDIM + (size_t)CPAD * FDIM);
    float* msq = xsq + BDIM;

    (void)hipFuncSetAttribute((const void*)nscm_gemm,
                              hipFuncAttributeMaxDynamicSharedMemorySize,
                              LDS_BYTES);

    convert_rows<<<BDIM + CPAD, 256, 0, stream>>>(x, means, Xq, Mq, xsq, msq);

    nscm_gemm<<<NWG, 512, LDS_BYTES, stream>>>(Xq, Mq, xsq, msq, out);
}